// Round 11
// baseline (189.921 us; speedup 1.0000x reference)
//
#include <hip/hip_runtime.h>
#include <hip/hip_bf16.h>
#include <math.h>

// Problem constants: B=4, T=2048, K(head dim)=128, H=8
#define T_SEQ 2048
#define NH 8
#define DK 128
#define BATCH 4
#define KT 64     // attention KV tile
#define QTILE 128 // Q rows per block (4 waves x 32 rows)
#define NT (T_SEQ / KT)

// Q pre-scale: (1/sqrt(128)) * log2(e)  -> S feeds exp2 directly
#define QSCALE 0.1275174435f

typedef __attribute__((ext_vector_type(8))) short short8;
typedef __attribute__((ext_vector_type(4))) float floatx4;
typedef __attribute__((ext_vector_type(16))) float floatx16;
typedef __attribute__((ext_vector_type(8))) _Float16 half8;

typedef const __attribute__((address_space(1))) unsigned int gu32_t;
typedef __attribute__((address_space(3))) unsigned int lu32_t;

#if defined(__has_builtin)
#if __has_builtin(__builtin_amdgcn_exp2f)
#define EXP2F(x) __builtin_amdgcn_exp2f(x)
#endif
#endif
#ifndef EXP2F
#define EXP2F(x) exp2f(x)
#endif

__device__ __forceinline__ unsigned short f2bf(float f) {
  union { float f; unsigned u; } v; v.f = f;
  unsigned u = v.u;
  return (unsigned short)((u + 0x7fffu + ((u >> 16) & 1u)) >> 16);  // RNE
}

__device__ __forceinline__ unsigned short f2h(float f) {
  union { _Float16 h; unsigned short u; } v; v.h = (_Float16)f;
  return v.u;
}

__device__ __forceinline__ unsigned pk2bf(float a, float b) {
  __hip_bfloat162 h = __float22bfloat162_rn(make_float2(a, b));
  return *(unsigned*)&h;   // low 16 = a, high 16 = b
}

__device__ __forceinline__ unsigned pkh(float a, float b) {
  union { _Float16 h[2]; unsigned u; } v;
  v.h[0] = (_Float16)a; v.h[1] = (_Float16)b;
  return v.u;
}

// ---------------------------------------------------------------------------
// Kernel 0: one-time fp32 -> bf16 conversion of Wq(xQSCALE), Wk, Wv, Wu AND x.
// (round-10 verbatim)
// ---------------------------------------------------------------------------
__global__ __launch_bounds__(256) void convert_kernel(
    const float* __restrict__ x,
    const float* __restrict__ Wq, const float* __restrict__ Wk,
    const float* __restrict__ Wv, const float* __restrict__ Wu,
    unsigned short* __restrict__ xb,
    unsigned short* __restrict__ Wqb, unsigned short* __restrict__ Wkb,
    unsigned short* __restrict__ Wvb, unsigned short* __restrict__ Wub)
{
  int bidx = blockIdx.x;
  const float* src;
  unsigned short* dst;
  float s = 1.0f;
  size_t off;
  if (bidx < 256) {
    int which = bidx >> 6;
    src = (which == 0) ? Wq : (which == 1) ? Wk : (which == 2) ? Wv : Wu;
    dst = (which == 0) ? Wqb : (which == 1) ? Wkb : (which == 2) ? Wvb : Wub;
    if (which == 0) s = QSCALE;
    off = ((size_t)(bidx & 63) * 256 + threadIdx.x) * 8;
  } else {
    src = x; dst = xb;
    off = ((size_t)(bidx - 256) * 256 + threadIdx.x) * 8;
  }
  float4 a = *(const float4*)(src + off);
  float4 c = *(const float4*)(src + off + 4);
  uint4 o;
  o.x = pk2bf(a.x * s, a.y * s);
  o.y = pk2bf(a.z * s, a.w * s);
  o.z = pk2bf(c.x * s, c.y * s);
  o.w = pk2bf(c.z * s, c.w * s);
  *(uint4*)(dst + off) = o;
}

// ---------------------------------------------------------------------------
// Kernel 1: fused QKV projection (round-10 verbatim).
// ---------------------------------------------------------------------------
__global__ __launch_bounds__(256) void qkv_proj_kernel(
    const unsigned short* __restrict__ xb,
    const unsigned short* __restrict__ Wqb,
    const unsigned short* __restrict__ Wkb,
    const unsigned short* __restrict__ Wvb,
    unsigned short* __restrict__ Qw, unsigned short* __restrict__ Kw,
    unsigned short* __restrict__ Vt)
{
  __shared__ __align__(16) unsigned short Tile[128 * 136];   // 34.8 KB
  int h  = blockIdx.x;             // head = col block (128 cols)
  int nb = h * 128;
  int mb = blockIdx.y * 128;       // row base within 8192
  int w3 = blockIdx.z;             // 0=Q 1=K 2=V
  int b = mb >> 11, t0 = mb & (T_SEQ - 1);
  int t = threadIdx.x, wave = t >> 6, lane = t & 63;
  int n = lane & 15, q = lane >> 4;
  int srow = lane >> 4;            // readback row-subindex
  int scol = (lane & 15) * 8;      // readback col (shorts)

  const unsigned short* Wsrc = (w3 == 0) ? Wqb : ((w3 == 1) ? Wkb : Wvb);
  const unsigned short* Wb = Wsrc + (size_t)nb * DK;
  #pragma unroll
  for (int j = 0; j < 8; ++j) {
    int inst = wave * 8 + j;              // 32 insts cover 128 rows
    int row = inst * 4 + (lane >> 4);     // 4 rows per inst
    int ck = (lane & 15) ^ (row & 15);    // pre-swizzled source chunk
    __builtin_amdgcn_global_load_lds(
        (gu32_t*)(Wb + (size_t)row * DK + ck * 8),
        (lu32_t*)(&Tile[inst * 512]), 16, 0, 0);
  }

  // x A-fragments for this wave's 32 rows: direct bf16 short8 loads.
  short8 xa[2][4];
  #pragma unroll
  for (int rg = 0; rg < 2; ++rg) {
    const unsigned short* xr = xb + (size_t)(mb + wave*32 + rg*16 + n) * DK;
    #pragma unroll
    for (int kc = 0; kc < 4; ++kc)
      xa[rg][kc] = *(const short8*)(xr + kc*32 + q*8);
  }

  __syncthreads();   // W staged

  if (w3 < 2) {
    floatx4 acc[2][8];
    #pragma unroll
    for (int rg = 0; rg < 2; ++rg)
      #pragma unroll
      for (int cg = 0; cg < 8; ++cg)
        acc[rg][cg] = (floatx4){0.f, 0.f, 0.f, 0.f};
    #pragma unroll
    for (int kc = 0; kc < 4; ++kc) {
      int p = ((kc*4 + q) ^ n) * 8;       // swizzled chunk (shorts)
      #pragma unroll
      for (int cg = 0; cg < 8; ++cg) {
        short8 bk = *(const short8*)&Tile[(cg*16 + n)*DK + p];
        acc[0][cg] = __builtin_amdgcn_mfma_f32_16x16x32_bf16(xa[0][kc], bk, acc[0][cg], 0, 0, 0);
        acc[1][cg] = __builtin_amdgcn_mfma_f32_16x16x32_bf16(xa[1][kc], bk, acc[1][cg], 0, 0, 0);
      }
    }
    __syncthreads();   // all W reads done before C overwrites Tile
    #pragma unroll
    for (int rg = 0; rg < 2; ++rg)
      #pragma unroll
      for (int cg = 0; cg < 8; ++cg)
        #pragma unroll
        for (int r = 0; r < 4; ++r)
          Tile[(wave*32 + rg*16 + q*4 + r)*136 + cg*16 + n] = f2bf(acc[rg][cg][r]);
    __syncthreads();
    unsigned short* gb = ((w3 == 0) ? Qw : Kw) +
        (((size_t)(b*NH + h))*T_SEQ + t0)*DK;
    #pragma unroll
    for (int i = 0; i < 8; ++i) {
      int row = wave*32 + i*4 + srow;
      *(uint4*)(gb + (size_t)row*DK + scol) = *(const uint4*)&Tile[row*136 + scol];
    }
  } else {
    // V: transposed C-tile (rows = d, cols = tt) via swapped operands
    floatx4 accv[8][2];
    #pragma unroll
    for (int mt = 0; mt < 8; ++mt)
      #pragma unroll
      for (int nt = 0; nt < 2; ++nt)
        accv[mt][nt] = (floatx4){0.f, 0.f, 0.f, 0.f};
    #pragma unroll
    for (int kc = 0; kc < 4; ++kc) {
      int p = ((kc*4 + q) ^ n) * 8;
      #pragma unroll
      for (int mt = 0; mt < 8; ++mt) {
        short8 wa = *(const short8*)&Tile[(mt*16 + n)*DK + p];
        accv[mt][0] = __builtin_amdgcn_mfma_f32_16x16x32_bf16(wa, xa[0][kc], accv[mt][0], 0, 0, 0);
        accv[mt][1] = __builtin_amdgcn_mfma_f32_16x16x32_bf16(wa, xa[1][kc], accv[mt][1], 0, 0, 0);
      }
    }
    __syncthreads();
    #pragma unroll
    for (int mt = 0; mt < 8; ++mt)
      #pragma unroll
      for (int nt = 0; nt < 2; ++nt)
        #pragma unroll
        for (int r = 0; r < 4; ++r)
          Tile[(mt*16 + q*4 + r)*136 + wave*32 + nt*16 + n] = f2h(accv[mt][nt][r]);
    __syncthreads();
    unsigned short* gb = Vt + ((size_t)(b*NH + h))*DK*T_SEQ + t0;
    #pragma unroll
    for (int i = 0; i < 8; ++i) {
      int d = wave*32 + i*4 + srow;
      *(uint4*)(gb + (size_t)d*T_SEQ + scol) = *(const uint4*)&Tile[d*136 + scol];
    }
  }
}

// ---------------------------------------------------------------------------
// Kernel 2: flash attention v6 — bank-conflict-free K/V swizzle.
// Change vs round-10 (only): fold row bits [4:3] into slot bits [1:0] on
// BOTH the staging source permutation and the read permutation:
//   K: slot = chunk ^ (row&15) ^ ((row>>3)&3)
//   V: slot = chunk ^ (row&7)  ^ ((row>>3)&3)
// Old swizzle left bank = slot*4 mod 32 independent of row (row strides
// 256B/128B are multiples of 128B) -> rows {x,x+8,x+16,x+24} collided.
// SQ_LDS_BANK_CONFLICT was saturated at 2^22 every round.
// ---------------------------------------------------------------------------
__global__ __launch_bounds__(256) void attn_kernel(
    const unsigned short* __restrict__ Qw, const unsigned short* __restrict__ Kw,
    const unsigned short* __restrict__ Vt, unsigned short* __restrict__ attn_out)
{
  __shared__ __align__(16) unsigned short Ks[2][KT * DK];   // 2 x 16 KB
  __shared__ __align__(16) unsigned short Vs[2][DK * KT];   // 2 x 16 KB
  int bid = blockIdx.x;
  int g5 = bid & 31, qt = bid >> 5;       // XCD-clustered: (b,h) fixed mod 32
  int h = g5 & 7, b = g5 >> 3;
  size_t base = ((size_t)(b * NH + h)) * T_SEQ * DK;
  const unsigned short* Qb = Qw + base;
  const unsigned short* Kb = Kw + base;
  const unsigned short* Vb = Vt + base;   // [128][2048] fp16
  int t = threadIdx.x, w = t >> 6, lane = t & 63;
  int l31 = lane & 31, l15 = lane & 15, hi = lane >> 5;
  int r43 = (l31 >> 3) & 3;               // row bits [4:3] for bank spread
  bool hb = (hi != 0);

  short8 qf[8];
  {
    const unsigned short* qr = Qb + (size_t)(qt*QTILE + w*32 + l31) * DK;
    #pragma unroll
    for (int kc = 0; kc < 8; ++kc)
      qf[kc] = *(const short8*)(qr + kc*16 + hi*8);
  }
  floatx16 Oacc[4];
  #pragma unroll
  for (int dt = 0; dt < 4; ++dt)
    #pragma unroll
    for (int r = 0; r < 16; ++r) Oacc[dt][r] = 0.f;
  float lp = 0.f;

  int kkey_lo = lane >> 4;
  int kck     = lane & 15;
  int vd_lo   = lane >> 3;
  int vck     = lane & 7;

  #define STAGE_K(KTI, BUFI)                                                    \
    {                                                                           \
      _Pragma("unroll")                                                         \
      for (int j = 0; j < 4; ++j) {                                             \
        int inst = w*4 + j;                                                     \
        int key = inst*4 + kkey_lo;                                             \
        int ck = kck ^ (key & 15) ^ ((key >> 3) & 3);                           \
        __builtin_amdgcn_global_load_lds(                                       \
            (gu32_t*)(Kb + ((size_t)((KTI)*KT + key))*DK + ck*8),               \
            (lu32_t*)(&Ks[BUFI][inst*512]), 16, 0, 0);                          \
      }                                                                         \
    }

  #define STAGE_V(KTI, BUFI)                                                    \
    {                                                                           \
      _Pragma("unroll")                                                         \
      for (int j = 0; j < 4; ++j) {                                             \
        int inst = w*4 + j;                                                     \
        int d = inst*8 + vd_lo;                                                 \
        int cvs = vck ^ (d & 7) ^ ((d >> 3) & 3);                               \
        __builtin_amdgcn_global_load_lds(                                       \
            (gu32_t*)(Vb + (size_t)d*T_SEQ + (KTI)*KT + cvs*8),                 \
            (lu32_t*)(&Vs[BUFI][inst*512]), 16, 0, 0);                          \
      }                                                                         \
    }

  STAGE_K(0, 0); STAGE_V(0, 0);
  STAGE_K(1, 1); STAGE_V(1, 1);

  for (int kt = 0; kt < NT; ++kt) {
    int buf = kt & 1;
    if (kt + 1 < NT) {
      asm volatile("s_waitcnt vmcnt(8)" ::: "memory");
    } else {
      asm volatile("s_waitcnt vmcnt(0)" ::: "memory");
    }
    __builtin_amdgcn_s_barrier();

    const unsigned short* KsL = &Ks[buf][0];
    const unsigned short* VsL = &Vs[buf][0];

    floatx16 st0, st1;
    #pragma unroll
    for (int r = 0; r < 16; ++r) { st0[r] = 0.f; st1[r] = 0.f; }
    __builtin_amdgcn_s_setprio(1);
    #pragma unroll
    for (int kc = 0; kc < 8; ++kc) {
      int cp = (2*kc + hi) ^ l15 ^ r43;
      short8 ak0 = *(const short8*)&KsL[(      l31)*DK + cp*8];
      short8 ak1 = *(const short8*)&KsL[(32 + l31)*DK + cp*8];
      st0 = __builtin_amdgcn_mfma_f32_32x32x16_bf16(ak0, qf[kc], st0, 0, 0, 0);
      st1 = __builtin_amdgcn_mfma_f32_32x32x16_bf16(ak1, qf[kc], st1, 0, 0, 0);
    }
    __builtin_amdgcn_s_setprio(0);
    #pragma unroll
    for (int g = 0; g < 2; ++g) {
      const floatx16& st = g ? st1 : st0;
      float e[16];
      #pragma unroll
      for (int r = 0; r < 16; ++r) e[r] = EXP2F(st[r]);
      float s = 0.f;
      #pragma unroll
      for (int r = 0; r < 16; ++r) s += e[r];
      lp += s;
      unsigned p[8];
      #pragma unroll
      for (int i = 0; i < 8; ++i) p[i] = pkh(e[2*i], e[2*i + 1]);
      #pragma unroll
      for (int m = 0; m < 2; ++m) {
        unsigned lo0 = p[4*m], lo1 = p[4*m + 1];
        unsigned up0 = p[4*m + 2], up1 = p[4*m + 3];
        unsigned s0 = hb ? lo0 : up0;
        unsigned s1 = hb ? lo1 : up1;
        unsigned r0 = __shfl_xor(s0, 32, 64);
        unsigned r1 = __shfl_xor(s1, 32, 64);
        union { half8 hv; unsigned u[4]; } fm;
        fm.u[0] = hb ? r0 : lo0;
        fm.u[1] = hb ? r1 : lo1;
        fm.u[2] = hb ? up0 : r0;
        fm.u[3] = hb ? up1 : r1;
        int cp = (4*g + 2*m + hi) ^ (l31 & 7) ^ r43;
        __builtin_amdgcn_s_setprio(1);
        #pragma unroll
        for (int dt = 0; dt < 4; ++dt) {
          int d = dt*32 + l31;
          half8 bv = *(const half8*)&VsL[d*KT + cp*8];
          Oacc[dt] = __builtin_amdgcn_mfma_f32_32x32x16_f16(fm.hv, bv, Oacc[dt], 0, 0, 0);
        }
        __builtin_amdgcn_s_setprio(0);
      }
    }
    __builtin_amdgcn_s_barrier();
    if (kt + 2 < NT) {
      STAGE_K(kt + 2, buf);
      STAGE_V(kt + 2, buf);
    }
  }
  float lpt = lp + __shfl_xor(lp, 32, 64);
  float rinv = 1.0f / lpt;
  float ri[16];
  #pragma unroll
  for (int r = 0; r < 16; ++r) {
    int row = (r & 3) + 8*(r >> 2) + 4*hi;
    ri[r] = __shfl(rinv, row, 64);
  }
  #pragma unroll
  for (int dt = 0; dt < 4; ++dt)
    #pragma unroll
    for (int r = 0; r < 16; ++r) {
      int row = (r & 3) + 8*(r >> 2) + 4*hi;
      int trow = qt*QTILE + w*32 + row;
      int col  = h*DK + dt*32 + l31;
      attn_out[((size_t)b*T_SEQ + trow)*1024 + col] = f2bf(Oacc[dt][r] * ri[r]);
    }
}

// ---------------------------------------------------------------------------
// Kernel 3: out = attn(8192,1024)bf16 @ Wu^T + bu (round-10 verbatim).
// ---------------------------------------------------------------------------
__global__ __launch_bounds__(256) void out_proj_kernel(
    const unsigned short* __restrict__ attnb, const unsigned short* __restrict__ Wub,
    const float* __restrict__ bu, float* __restrict__ out)
{
  int mb = blockIdx.x * 16;
  int t = threadIdx.x, wave = t >> 6, lane = t & 63;
  int n = lane & 15, q = lane >> 4;
  int nb2 = wave * 32;
  floatx4 acc[2];
  acc[0] = (floatx4){0.f,0.f,0.f,0.f};
  acc[1] = (floatx4){0.f,0.f,0.f,0.f};
  const unsigned short* ap = attnb + (size_t)(mb + n) * 1024;
  #pragma unroll 8
  for (int kc = 0; kc < 32; ++kc) {
    int ko = kc*32 + q*8;
    short8 a0 = *(const short8*)(ap + ko);
    #pragma unroll
    for (int cg = 0; cg < 2; ++cg) {
      short8 bw = *(const short8*)(Wub + (size_t)(nb2 + cg*16 + n) * 1024 + ko);
      acc[cg] = __builtin_amdgcn_mfma_f32_16x16x32_bf16(a0, bw, acc[cg], 0, 0, 0);
    }
  }
  #pragma unroll
  for (int cg = 0; cg < 2; ++cg)
    #pragma unroll
    for (int r = 0; r < 4; ++r) {
      int m = mb + q*4 + r;
      int c = nb2 + cg*16 + n;
      out[(size_t)m * 128 + c] = acc[cg][r] + bu[c];
    }
}

// ---------------------------------------------------------------------------
extern "C" void kernel_launch(void* const* d_in, const int* in_sizes, int n_in,
                              void* d_out, int out_size, void* d_ws, size_t ws_size,
                              hipStream_t stream) {
  const float* x  = (const float*)d_in[0];
  const float* Wq = (const float*)d_in[1];
  const float* Wk = (const float*)d_in[2];
  const float* Wv = (const float*)d_in[3];
  const float* Wu = (const float*)d_in[4];
  const float* bu = (const float*)d_in[5];
  float* out = (float*)d_out;

  const size_t NE  = (size_t)BATCH * NH * T_SEQ * DK;  // 8,388,608 elems
  const size_t WEL = (size_t)DK * DK * NH;             // 131,072 elems per W
  const size_t XEL = (size_t)BATCH * T_SEQ * DK;       // 1,048,576 elems (x)
  unsigned short* Qw   = (unsigned short*)d_ws;
  unsigned short* Kw   = Qw + NE;
  unsigned short* Vt   = Kw + NE;
  unsigned short* attn = Vt + NE;
  unsigned short* Wqb  = attn + NE;
  unsigned short* Wkb  = Wqb + WEL;
  unsigned short* Wvb  = Wkb + WEL;
  unsigned short* Wub  = Wvb + WEL;
  unsigned short* xb   = Wub + WEL;
  if (ws_size < (4 * NE + 4 * WEL + XEL) * sizeof(unsigned short)) return;

  convert_kernel<<<768, 256, 0, stream>>>(x, Wq, Wk, Wv, Wu,
                                          xb, Wqb, Wkb, Wvb, Wub);
  dim3 g1(8, 64, 3);
  qkv_proj_kernel<<<g1, 256, 0, stream>>>(xb, Wqb, Wkb, Wvb, Qw, Kw, Vt);
  attn_kernel<<<BATCH * NH * (T_SEQ / QTILE), 256, 0, stream>>>(Qw, Kw, Vt, attn);
  out_proj_kernel<<<BATCH * T_SEQ / 16, 256, 0, stream>>>(attn, Wub, bu, out);
}